// Round 1
// baseline (581.367 us; speedup 1.0000x reference)
//
#include <hip/hip_runtime.h>
#include <math.h>

#define RES 160
#define NSAMP 128
#define NEAR_T 0.1f
#define FAR_T 10.0f

__global__ __launch_bounds__(NSAMP) void plenoxel_kernel(
    const float* __restrict__ ray_o,
    const float* __restrict__ ray_d,
    const float* __restrict__ density,
    const float* __restrict__ sh,
    float* __restrict__ out_rgb,    // [R,3]
    float* __restrict__ out_depth,  // [R]
    float* __restrict__ out_acc,    // [R]
    int R)
{
    const int r = blockIdx.x;
    const int s = threadIdx.x;
    if (r >= R) return;

    const float ox = ray_o[r * 3 + 0], oy = ray_o[r * 3 + 1], oz = ray_o[r * 3 + 2];
    const float dx = ray_d[r * 3 + 0], dy = ray_d[r * 3 + 1], dz = ray_d[r * 3 + 2];

    // per-ray SH deg-2 basis (cheap; every thread computes it)
    const float dn  = sqrtf(dx * dx + dy * dy + dz * dz);
    const float inv = 1.0f / (dn + 1e-8f);
    const float nx = dx * inv, ny = dy * inv, nz = dz * inv;
    float basis[9];
    basis[0] = 0.28209479177387814f;
    basis[1] = -0.48860251190291987f * ny;
    basis[2] =  0.48860251190291987f * nz;
    basis[3] = -0.48860251190291987f * nx;
    basis[4] =  1.0925484305920792f * nx * ny;
    basis[5] = -1.0925484305920792f * ny * nz;
    basis[6] =  0.31539156525252005f * (2.0f * nz * nz - nx * nx - ny * ny);
    basis[7] = -1.0925484305920792f * nx * nz;
    basis[8] =  0.5462742152960396f * (nx * nx - ny * ny);

    // t sample + dist (linspace NEAR..FAR, NSAMP)
    const float step = (FAR_T - NEAR_T) / (float)(NSAMP - 1);
    const float t  = NEAR_T + step * (float)s;
    const float tn = NEAR_T + step * (float)(s + 1);
    float dist = (s == NSAMP - 1) ? 1e10f : (tn - t);
    dist *= dn;

    // sample point -> voxel coords
    const float px = ox + t * dx, py = oy + t * dy, pz = oz + t * dz;
    float vx = (px + 1.0f) / 2.0f * (float)RES;
    float vy = (py + 1.0f) / 2.0f * (float)RES;
    float vz = (pz + 1.0f) / 2.0f * (float)RES;
    vx = fminf(fmaxf(vx, 0.0f), (float)(RES - 1));
    vy = fminf(fmaxf(vy, 0.0f), (float)(RES - 1));
    vz = fminf(fmaxf(vz, 0.0f), (float)(RES - 1));
    const float flx = floorf(vx), fly = floorf(vy), flz = floorf(vz);
    const int x0 = (int)flx, y0 = (int)fly, z0 = (int)flz;
    const int x1 = min(x0 + 1, RES - 1);
    const int y1 = min(y0 + 1, RES - 1);
    const int z1 = min(z0 + 1, RES - 1);
    const float fx = vx - flx, fy = vy - fly, fz = vz - flz;

    const float wx[2] = { 1.0f - fx, fx };
    const float wy[2] = { 1.0f - fy, fy };
    const float wz[2] = { 1.0f - fz, fz };
    const int   xi[2] = { x0, x1 };
    const int   yi[2] = { y0, y1 };
    const int   zi[2] = { z0, z1 };

    float dens = 0.0f;
    float c0 = 0.0f, c1 = 0.0f, c2 = 0.0f;

    // corner order matches reference: x outer, y mid, z inner
    #pragma unroll
    for (int k = 0; k < 8; ++k) {
        const int xb = (k >> 2) & 1;
        const int yb = (k >> 1) & 1;
        const int zb =  k       & 1;
        const float w = wx[xb] * wy[yb] * wz[zb];
        const int vidx = (zi[zb] * RES + yi[yb]) * RES + xi[xb];
        dens += w * density[vidx];
        const float* __restrict__ base = sh + (long long)vidx * 27;
        float d0 = 0.0f, d1 = 0.0f, d2 = 0.0f;
        #pragma unroll
        for (int j = 0; j < 9; ++j) {
            d0 += base[0 * 9 + j] * basis[j];
            d1 += base[1 * 9 + j] * basis[j];
            d2 += base[2 * 9 + j] * basis[j];
        }
        c0 += w * d0;
        c1 += w * d1;
        c2 += w * d2;
    }

    // colors
    const float col0 = 1.0f / (1.0f + expf(-c0));
    const float col1 = 1.0f / (1.0f + expf(-c1));
    const float col2 = 1.0f / (1.0f + expf(-c2));

    // alpha
    const float alpha = 1.0f - expf(-fmaxf(dens, 0.0f) * dist);
    const float om = 1.0f - alpha + 1e-10f;

    // exclusive prefix product of om across 128 samples (Hillis-Steele in LDS)
    __shared__ float sbuf[NSAMP];
    sbuf[s] = om;
    __syncthreads();
    #pragma unroll
    for (int off = 1; off < NSAMP; off <<= 1) {
        const float prev = (s >= off) ? sbuf[s - off] : 1.0f;
        __syncthreads();
        sbuf[s] *= prev;
        __syncthreads();
    }
    const float trans = (s == 0) ? 1.0f : sbuf[s - 1];
    const float wgt = alpha * trans;

    // block reduction of 5 values: w*rgb, w*t, w
    float v0 = wgt * col0, v1 = wgt * col1, v2 = wgt * col2, v3 = wgt * t, v4 = wgt;
    #pragma unroll
    for (int off = 32; off > 0; off >>= 1) {
        v0 += __shfl_down(v0, off, 64);
        v1 += __shfl_down(v1, off, 64);
        v2 += __shfl_down(v2, off, 64);
        v3 += __shfl_down(v3, off, 64);
        v4 += __shfl_down(v4, off, 64);
    }
    __shared__ float part[2][5];
    if ((s & 63) == 0) {
        const int wv = s >> 6;
        part[wv][0] = v0; part[wv][1] = v1; part[wv][2] = v2;
        part[wv][3] = v3; part[wv][4] = v4;
    }
    __syncthreads();
    if (s == 0) {
        out_rgb[r * 3 + 0] = part[0][0] + part[1][0];
        out_rgb[r * 3 + 1] = part[0][1] + part[1][1];
        out_rgb[r * 3 + 2] = part[0][2] + part[1][2];
        out_depth[r]       = part[0][3] + part[1][3];
        out_acc[r]         = part[0][4] + part[1][4];
    }
}

extern "C" void kernel_launch(void* const* d_in, const int* in_sizes, int n_in,
                              void* d_out, int out_size, void* d_ws, size_t ws_size,
                              hipStream_t stream) {
    const float* ray_o   = (const float*)d_in[0];
    const float* ray_d   = (const float*)d_in[1];
    const float* density = (const float*)d_in[2];
    const float* sh      = (const float*)d_in[3];
    const int R = in_sizes[0] / 3;

    float* out_rgb   = (float*)d_out;
    float* out_depth = out_rgb + (size_t)R * 3;
    float* out_acc   = out_depth + R;

    plenoxel_kernel<<<R, NSAMP, 0, stream>>>(ray_o, ray_d, density, sh,
                                             out_rgb, out_depth, out_acc, R);
}

// Round 2
// 536.542 us; speedup vs baseline: 1.0835x; 1.0835x over previous
//
#include <hip/hip_runtime.h>
#include <math.h>

#define RES 160
#define NSAMP 128
#define NEAR_T 0.1f
#define FAR_T 10.0f

__global__ __launch_bounds__(NSAMP) void plenoxel_kernel(
    const float* __restrict__ ray_o,
    const float* __restrict__ ray_d,
    const float* __restrict__ density,
    const float* __restrict__ sh,
    float* __restrict__ out_rgb,    // [R,3]
    float* __restrict__ out_depth,  // [R]
    float* __restrict__ out_acc,    // [R]
    int R)
{
    const int r = blockIdx.x;
    const int s = threadIdx.x;       // sample index, 0..127
    const int lane = s & 63;
    if (r >= R) return;

    const float ox = ray_o[r * 3 + 0], oy = ray_o[r * 3 + 1], oz = ray_o[r * 3 + 2];
    const float dx = ray_d[r * 3 + 0], dy = ray_d[r * 3 + 1], dz = ray_d[r * 3 + 2];

    // per-ray SH deg-2 basis
    const float dn  = sqrtf(dx * dx + dy * dy + dz * dz);
    const float inv = 1.0f / (dn + 1e-8f);
    const float nx = dx * inv, ny = dy * inv, nz = dz * inv;
    float basis[9];
    basis[0] = 0.28209479177387814f;
    basis[1] = -0.48860251190291987f * ny;
    basis[2] =  0.48860251190291987f * nz;
    basis[3] = -0.48860251190291987f * nx;
    basis[4] =  1.0925484305920792f * nx * ny;
    basis[5] = -1.0925484305920792f * ny * nz;
    basis[6] =  0.31539156525252005f * (2.0f * nz * nz - nx * nx - ny * ny);
    basis[7] = -1.0925484305920792f * nx * nz;
    basis[8] =  0.5462742152960396f * (nx * nx - ny * ny);

    // t sample + dist
    const float step = (FAR_T - NEAR_T) / (float)(NSAMP - 1);
    const float t = NEAR_T + step * (float)s;
    float dist = (s == NSAMP - 1) ? 1e10f : step;
    dist *= dn;

    // sample point -> voxel coords
    const float px = ox + t * dx, py = oy + t * dy, pz = oz + t * dz;
    float vx = (px + 1.0f) * 0.5f * (float)RES;
    float vy = (py + 1.0f) * 0.5f * (float)RES;
    float vz = (pz + 1.0f) * 0.5f * (float)RES;
    vx = fminf(fmaxf(vx, 0.0f), (float)(RES - 1));
    vy = fminf(fmaxf(vy, 0.0f), (float)(RES - 1));
    vz = fminf(fmaxf(vz, 0.0f), (float)(RES - 1));
    const float flx = floorf(vx), fly = floorf(vy), flz = floorf(vz);
    const int x0 = (int)flx, y0 = (int)fly, z0 = (int)flz;
    const int x1 = min(x0 + 1, RES - 1);
    const int y1 = min(y0 + 1, RES - 1);
    const int z1 = min(z0 + 1, RES - 1);
    const float fx = vx - flx, fy = vy - fly, fz = vz - flz;

    const float wx[2] = { 1.0f - fx, fx };
    const float wy[2] = { 1.0f - fy, fy };
    const float wz[2] = { 1.0f - fz, fz };
    const int   xi[2] = { x0, x1 };
    const int   yi[2] = { y0, y1 };
    const int   zi[2] = { z0, z1 };

    float dens = 0.0f;
    float c0 = 0.0f, c1 = 0.0f, c2 = 0.0f;

    #pragma unroll
    for (int k = 0; k < 8; ++k) {
        const int xb = (k >> 2) & 1;
        const int yb = (k >> 1) & 1;
        const int zb =  k       & 1;
        const float w = wx[xb] * wy[yb] * wz[zb];
        const int vidx = (zi[zb] * RES + yi[yb]) * RES + xi[xb];
        dens += w * density[vidx];
        const float* base = sh + (size_t)vidx * 27;
        // wide (dwordx4/x2) loads instead of 27 scalar gathers
        float c[27];
        __builtin_memcpy(c, base, sizeof(c));
        float d0 = 0.0f, d1 = 0.0f, d2 = 0.0f;
        #pragma unroll
        for (int j = 0; j < 9; ++j) {
            d0 += c[j]      * basis[j];
            d1 += c[9 + j]  * basis[j];
            d2 += c[18 + j] * basis[j];
        }
        c0 += w * d0;
        c1 += w * d1;
        c2 += w * d2;
    }

    // colors (fast sigmoid)
    const float col0 = 1.0f / (1.0f + __expf(-c0));
    const float col1 = 1.0f / (1.0f + __expf(-c1));
    const float col2 = 1.0f / (1.0f + __expf(-c2));

    // alpha
    const float alpha = 1.0f - __expf(-fmaxf(dens, 0.0f) * dist);
    const float om = 1.0f - alpha + 1e-10f;

    // exclusive prefix product of om across 128 samples:
    // wave-level inclusive shfl-scan (6 steps, no barriers) + 1 cross-wave combine
    float incl = om;
    #pragma unroll
    for (int off = 1; off < 64; off <<= 1) {
        const float u = __shfl_up(incl, off, 64);
        incl *= (lane >= off) ? u : 1.0f;
    }
    float excl = __shfl_up(incl, 1, 64);
    if (lane == 0) excl = 1.0f;

    __shared__ float w0tot;
    if (s == 63) w0tot = incl;   // product of samples 0..63
    __syncthreads();
    const float trans = (s < 64) ? excl : excl * w0tot;
    const float wgt = alpha * trans;

    // block reduction of 5 values
    float v0 = wgt * col0, v1 = wgt * col1, v2 = wgt * col2, v3 = wgt * t, v4 = wgt;
    #pragma unroll
    for (int off = 32; off > 0; off >>= 1) {
        v0 += __shfl_down(v0, off, 64);
        v1 += __shfl_down(v1, off, 64);
        v2 += __shfl_down(v2, off, 64);
        v3 += __shfl_down(v3, off, 64);
        v4 += __shfl_down(v4, off, 64);
    }
    __shared__ float part[2][5];
    if (lane == 0) {
        const int wv = s >> 6;
        part[wv][0] = v0; part[wv][1] = v1; part[wv][2] = v2;
        part[wv][3] = v3; part[wv][4] = v4;
    }
    __syncthreads();
    if (s == 0) {
        out_rgb[r * 3 + 0] = part[0][0] + part[1][0];
        out_rgb[r * 3 + 1] = part[0][1] + part[1][1];
        out_rgb[r * 3 + 2] = part[0][2] + part[1][2];
        out_depth[r]       = part[0][3] + part[1][3];
        out_acc[r]         = part[0][4] + part[1][4];
    }
}

extern "C" void kernel_launch(void* const* d_in, const int* in_sizes, int n_in,
                              void* d_out, int out_size, void* d_ws, size_t ws_size,
                              hipStream_t stream) {
    const float* ray_o   = (const float*)d_in[0];
    const float* ray_d   = (const float*)d_in[1];
    const float* density = (const float*)d_in[2];
    const float* sh      = (const float*)d_in[3];
    const int R = in_sizes[0] / 3;

    float* out_rgb   = (float*)d_out;
    float* out_depth = out_rgb + (size_t)R * 3;
    float* out_acc   = out_depth + R;

    plenoxel_kernel<<<R, NSAMP, 0, stream>>>(ray_o, ray_d, density, sh,
                                             out_rgb, out_depth, out_acc, R);
}

// Round 3
// 523.718 us; speedup vs baseline: 1.1101x; 1.0245x over previous
//
#include <hip/hip_runtime.h>
#include <math.h>

#define RES 160
#define NSAMP 128
#define NEAR_T 0.1f
#define FAR_T 10.0f

typedef float float4v __attribute__((ext_vector_type(4)));

__global__ __launch_bounds__(1024) void plenoxel_kernel(
    const float* __restrict__ ray_o,
    const float* __restrict__ ray_d,
    const float* __restrict__ density,
    const float* __restrict__ sh,
    float* __restrict__ out_rgb,    // [R,3]
    float* __restrict__ out_depth,  // [R]
    float* __restrict__ out_acc,    // [R]
    int R)
{
    const int r   = blockIdx.x;
    const int tid = threadIdx.x;    // 0..1023
    const int s   = tid >> 3;       // sample index 0..127
    const int e   = tid & 7;        // element lane within sample group
    if (r >= R) return;

    const float ox = ray_o[r * 3 + 0], oy = ray_o[r * 3 + 1], oz = ray_o[r * 3 + 2];
    const float dx = ray_d[r * 3 + 0], dy = ray_d[r * 3 + 1], dz = ray_d[r * 3 + 2];

    // per-ray SH deg-2 basis
    const float dn  = sqrtf(dx * dx + dy * dy + dz * dz);
    const float inv = 1.0f / (dn + 1e-8f);
    const float nx = dx * inv, ny = dy * inv, nz = dz * inv;
    const float b0 = 0.28209479177387814f;
    const float b1 = -0.48860251190291987f * ny;
    const float b2 =  0.48860251190291987f * nz;
    const float b3 = -0.48860251190291987f * nx;
    const float b4 =  1.0925484305920792f * nx * ny;
    const float b5 = -1.0925484305920792f * ny * nz;
    const float b6 =  0.31539156525252005f * (2.0f * nz * nz - nx * nx - ny * ny);
    const float b7 = -1.0925484305920792f * nx * nz;
    const float b8 =  0.5462742152960396f * (nx * nx - ny * ny);

    // per-lane channel-masked basis vectors.
    // lane e covers SH row floats [offE, offE+3], offE = {0,4,8,12,16,20,23,23}
    // row layout: floats 0-8 = ch0, 9-17 = ch1, 18-26 = ch2
    float4v bLo = {0.f, 0.f, 0.f, 0.f}, bHi = {0.f, 0.f, 0.f, 0.f};
    int chLo = 3, chHi = 3;   // 3 = none
    switch (e) {
        case 0: bLo = (float4v){b0, b1, b2, b3}; chLo = 0; break;
        case 1: bLo = (float4v){b4, b5, b6, b7}; chLo = 0; break;
        case 2: bLo = (float4v){b8, 0.f, 0.f, 0.f}; bHi = (float4v){0.f, b0, b1, b2};
                chLo = 0; chHi = 1; break;
        case 3: bLo = (float4v){b3, b4, b5, b6}; chLo = 1; break;
        case 4: bLo = (float4v){b7, b8, 0.f, 0.f}; bHi = (float4v){0.f, 0.f, b0, b1};
                chLo = 1; chHi = 2; break;
        case 5: bLo = (float4v){b2, b3, b4, b5}; chLo = 2; break;
        case 6: bLo = (float4v){0.f, b6, b7, b8}; chLo = 2; break; // float 23 dup zeroed
        default: break;                                            // lane 7: density only
    }
    const int offE = (e >= 6) ? 23 : 4 * e;

    // sample geometry (all 8 lanes of a group compute identically)
    const float step = (FAR_T - NEAR_T) / (float)(NSAMP - 1);
    const float t = NEAR_T + step * (float)s;
    const float px = ox + t * dx, py = oy + t * dy, pz = oz + t * dz;
    float vx = (px + 1.0f) * 0.5f * (float)RES;
    float vy = (py + 1.0f) * 0.5f * (float)RES;
    float vz = (pz + 1.0f) * 0.5f * (float)RES;
    vx = fminf(fmaxf(vx, 0.0f), (float)(RES - 1));
    vy = fminf(fmaxf(vy, 0.0f), (float)(RES - 1));
    vz = fminf(fmaxf(vz, 0.0f), (float)(RES - 1));
    const float flx = floorf(vx), fly = floorf(vy), flz = floorf(vz);
    const int x0 = (int)flx, y0 = (int)fly, z0 = (int)flz;
    const int x1 = min(x0 + 1, RES - 1);
    const int y1 = min(y0 + 1, RES - 1);
    const int z1 = min(z0 + 1, RES - 1);
    const float fx = vx - flx, fy = vy - fly, fz = vz - flz;

    const float wx0 = 1.0f - fx, wx1 = fx;
    const float wy0 = 1.0f - fy, wy1 = fy;
    const float wz0 = 1.0f - fz, wz1 = fz;

    // corner k: xb = k>>2, yb = (k>>1)&1, zb = k&1 (reference order)
    const int zy00 = (z0 * RES + y0) * RES;
    const int zy01 = (z0 * RES + y1) * RES;
    const int zy10 = (z1 * RES + y0) * RES;
    const int zy11 = (z1 * RES + y1) * RES;
    int   vidx[8];
    float w8[8];
    vidx[0] = zy00 + x0; w8[0] = wx0 * wy0 * wz0;
    vidx[1] = zy10 + x0; w8[1] = wx0 * wy0 * wz1;
    vidx[2] = zy01 + x0; w8[2] = wx0 * wy1 * wz0;
    vidx[3] = zy11 + x0; w8[3] = wx0 * wy1 * wz1;
    vidx[4] = zy00 + x1; w8[4] = wx1 * wy0 * wz0;
    vidx[5] = zy10 + x1; w8[5] = wx1 * wy0 * wz1;
    vidx[6] = zy01 + x1; w8[6] = wx1 * wy1 * wz0;
    vidx[7] = zy11 + x1; w8[7] = wx1 * wy1 * wz1;

    // density: lane e fetches corner e's density (1 scattered instr per sample)
    float vD = w8[e] * density[vidx[e]];

    // SH: per corner, the 8-lane group loads the 27-float row cooperatively
    float accLo = 0.0f, accHi = 0.0f;
    #pragma unroll
    for (int k = 0; k < 8; ++k) {
        const float* p = sh + (size_t)vidx[k] * 27 + offE;
        float4v row = *(const float4v*)p;   // 4B-aligned dwordx4 (HW unaligned OK)
        const float tl = row.x * bLo.x + row.y * bLo.y + row.z * bLo.z + row.w * bLo.w;
        const float th = row.x * bHi.x + row.y * bHi.y + row.z * bHi.z + row.w * bHi.w;
        accLo = fmaf(tl, w8[k], accLo);
        accHi = fmaf(th, w8[k], accHi);
    }

    // scatter partials to (c0,c1,c2,dens) and butterfly-reduce over the 8 lanes
    float v0 = ((chLo == 0) ? accLo : 0.0f) + ((chHi == 0) ? accHi : 0.0f);
    float v1 = ((chLo == 1) ? accLo : 0.0f) + ((chHi == 1) ? accHi : 0.0f);
    float v2 = ((chLo == 2) ? accLo : 0.0f) + ((chHi == 2) ? accHi : 0.0f);
    float v3 = vD;
    #pragma unroll
    for (int m = 1; m < 8; m <<= 1) {
        v0 += __shfl_xor(v0, m, 64);
        v1 += __shfl_xor(v1, m, 64);
        v2 += __shfl_xor(v2, m, 64);
        v3 += __shfl_xor(v3, m, 64);
    }

    __shared__ float4v sdata[NSAMP];
    if (e == 0) sdata[s] = (float4v){v0, v1, v2, v3};
    __syncthreads();

    // ---- epilogue on first 128 threads (waves 0,1) ----
    float incl = 1.0f, alpha = 0.0f, col0 = 0.f, col1 = 0.f, col2 = 0.f, ts = 0.f;
    const int lane = tid & 63;
    if (tid < NSAMP) {
        const float4v d = sdata[tid];
        col0 = 1.0f / (1.0f + __expf(-d.x));
        col1 = 1.0f / (1.0f + __expf(-d.y));
        col2 = 1.0f / (1.0f + __expf(-d.z));
        ts = NEAR_T + step * (float)tid;
        float dist = ((tid == NSAMP - 1) ? 1e10f : step) * dn;
        alpha = 1.0f - __expf(-fmaxf(d.w, 0.0f) * dist);
        const float om = 1.0f - alpha + 1e-10f;
        incl = om;
        #pragma unroll
        for (int off = 1; off < 64; off <<= 1) {
            const float u = __shfl_up(incl, off, 64);
            incl *= (lane >= off) ? u : 1.0f;
        }
    }
    __shared__ float w0tot;
    if (tid == 63) w0tot = incl;
    __syncthreads();

    __shared__ float part[2][5];
    if (tid < NSAMP) {
        float excl = __shfl_up(incl, 1, 64);
        if (lane == 0) excl = 1.0f;
        const float trans = (tid < 64) ? excl : excl * w0tot;
        const float wgt = alpha * trans;
        float u0 = wgt * col0, u1 = wgt * col1, u2 = wgt * col2, u3 = wgt * ts, u4 = wgt;
        #pragma unroll
        for (int off = 32; off > 0; off >>= 1) {
            u0 += __shfl_down(u0, off, 64);
            u1 += __shfl_down(u1, off, 64);
            u2 += __shfl_down(u2, off, 64);
            u3 += __shfl_down(u3, off, 64);
            u4 += __shfl_down(u4, off, 64);
        }
        if (lane == 0) {
            const int wv = tid >> 6;
            part[wv][0] = u0; part[wv][1] = u1; part[wv][2] = u2;
            part[wv][3] = u3; part[wv][4] = u4;
        }
    }
    __syncthreads();
    if (tid == 0) {
        out_rgb[r * 3 + 0] = part[0][0] + part[1][0];
        out_rgb[r * 3 + 1] = part[0][1] + part[1][1];
        out_rgb[r * 3 + 2] = part[0][2] + part[1][2];
        out_depth[r]       = part[0][3] + part[1][3];
        out_acc[r]         = part[0][4] + part[1][4];
    }
}

extern "C" void kernel_launch(void* const* d_in, const int* in_sizes, int n_in,
                              void* d_out, int out_size, void* d_ws, size_t ws_size,
                              hipStream_t stream) {
    const float* ray_o   = (const float*)d_in[0];
    const float* ray_d   = (const float*)d_in[1];
    const float* density = (const float*)d_in[2];
    const float* sh      = (const float*)d_in[3];
    const int R = in_sizes[0] / 3;

    float* out_rgb   = (float*)d_out;
    float* out_depth = out_rgb + (size_t)R * 3;
    float* out_acc   = out_depth + R;

    plenoxel_kernel<<<R, 1024, 0, stream>>>(ray_o, ray_d, density, sh,
                                            out_rgb, out_depth, out_acc, R);
}